// Round 11
// baseline (140.076 us; speedup 1.0000x reference)
//
#include <hip/hip_runtime.h>
#include <math.h>

#define BB   32
#define CIN  16
#define HH   64
#define SS   128

// ---------------------------------------------------------------------------
// Composite-weight front-end:  h_pre[n][p] = sum_{c,ti} T[n][c][ti]*xpad[c][p+off(ti)]
//                                            + B_eff[n][p];  h = relu(h_pre)
// taps off(ti), ti=0..10: {-10,-5,-3,-2,-1,0,1,2,3,5,10}
//   x1 path (w12 o w11):  ti {2,5,8}   x2 (w22 o w21): ti {0,1,5,9,10}
//   x3 (w31 direct):      ti {3,4,5,6,7}
// B_eff folds all biases incl. SAME-padding in-range indicators (position dep).
// All composites in f64 (deviation ~1e-15 << decision margins).
// ---------------------------------------------------------------------------

// prep1: W1e[m][c][t]=sum_mm w12[m][mm][t]*w11[mm][c]; W2e likewise (w22,w21);
//        SW1[m][t]=sum_mm w12[m][mm][t]*b11[mm]; SW2[m][u]=sum w22*b21.
__global__ __launch_bounds__(256) void prep1(
    const float* __restrict__ w11, const float* __restrict__ w21,
    const float* __restrict__ w12, const float* __restrict__ w22,
    const float* __restrict__ b11, const float* __restrict__ b21,
    double* __restrict__ W1e, double* __restrict__ W2e,
    double* __restrict__ SW1, double* __restrict__ SW2)
{
    int o = blockIdx.x * 256 + threadIdx.x;
    if (o < 3072) {
        int m = o / 48, r = o % 48, c = r / 3, t = r % 3;
        double a0 = 0, a1 = 0;
        for (int mm = 0; mm < 64; mm += 2) {
            a0 += (double)w12[(m*64+mm)*3+t]   * (double)w11[mm*16+c];
            a1 += (double)w12[(m*64+mm+1)*3+t] * (double)w11[(mm+1)*16+c];
        }
        W1e[o] = a0 + a1;
    } else if (o < 8192) {
        int j = o - 3072;
        int m = j / 80, r = j % 80, c = r / 5, u = r % 5;
        double a0 = 0, a1 = 0;
        for (int mm = 0; mm < 64; mm += 2) {
            a0 += (double)w22[(m*64+mm)*5+u]   * (double)w21[mm*16+c];
            a1 += (double)w22[(m*64+mm+1)*5+u] * (double)w21[(mm+1)*16+c];
        }
        W2e[j] = a0 + a1;
    } else if (o < 8384) {
        int j = o - 8192; int m = j / 3, t = j % 3;
        double a = 0;
        for (int mm = 0; mm < 64; ++mm)
            a += (double)w12[(m*64+mm)*3+t] * (double)b11[mm];
        SW1[j] = a;
    } else if (o < 8704) {
        int j = o - 8384; int m = j / 5, u = j % 5;
        double a = 0;
        for (int mm = 0; mm < 64; ++mm)
            a += (double)w22[(m*64+mm)*5+u] * (double)b21[mm];
        SW2[j] = a;
    }
}

// prep2: T[(c*11+ti)*64+n], Be[p*64+n]
__global__ __launch_bounds__(256) void prep2(
    const float* __restrict__ wf,  const float* __restrict__ bf,
    const float* __restrict__ b12, const float* __restrict__ b22,
    const float* __restrict__ b31, const float* __restrict__ w31,
    const double* __restrict__ W1e, const double* __restrict__ W2e,
    const double* __restrict__ SW1, const double* __restrict__ SW2,
    double* __restrict__ T, double* __restrict__ Be)
{
    int o = blockIdx.x * 256 + threadIdx.x;
    if (o < 11264) {
        int n = o & 63, k = o >> 6, c = k / 11, ti = k % 11;
        double a = 0;
        if (ti == 2 || ti == 5 || ti == 8) {
            int t = (ti - 2) / 3;
            for (int m = 0; m < 64; ++m)
                a += (double)wf[n*192+m] * W1e[m*48 + c*3 + t];
        }
        if (ti == 0 || ti == 1 || ti == 5 || ti == 9 || ti == 10) {
            int u = (ti == 0) ? 0 : (ti == 1) ? 1 : (ti == 5) ? 2 : (ti == 9) ? 3 : 4;
            for (int m = 0; m < 64; ++m)
                a += (double)wf[n*192+64+m] * W2e[m*80 + c*5 + u];
        }
        if (ti >= 3 && ti <= 7) {
            int v = ti - 3;
            for (int m = 0; m < 64; ++m)
                a += (double)wf[n*192+128+m] * (double)w31[(m*16+c)*5+v];
        }
        T[k*64+n] = a;
    } else if (o < 19456) {
        int j = o - 11264; int n = j & 63, p = j >> 6;
        double a = (double)bf[n];
        for (int m = 0; m < 64; ++m) {
            double bias1 = (double)b12[m];
            for (int t = 0; t < 3; ++t) {
                int pos = p + (t - 1) * 3;
                if (pos >= 0 && pos < SS) bias1 += SW1[m*3+t];
            }
            double bias2 = (double)b22[m];
            for (int u = 0; u < 5; ++u) {
                int pos = p + (u - 2) * 5;
                if (pos >= 0 && pos < SS) bias2 += SW2[m*5+u];
            }
            a += (double)wf[n*192+m]     * bias1
               + (double)wf[n*192+64+m]  * bias2
               + (double)wf[n*192+128+m] * (double)b31[m];
        }
        Be[p*64+n] = a;
    }
}

// ---------------------------------------------------------------------------
// front: 512 thr = 8 waves = (kq 0..3) x (ph 0..1). lane = channel n.
// Conv: E f32 [176 k][16 p]; wave reads its k-quarter, its p-half (each elem
// read ONCE, as float4). Weights T in regs (44 f64). f64 acc. Then 4-way kq
// reduction -> +B_eff, relu -> h f64 [64][18]. QP: w1 rows in regs, h double2
// broadcast reads, Q&P share data read. Reductions via red[4][16][64].
// ---------------------------------------------------------------------------
__global__ __launch_bounds__(512, 1) void front(
    const float* __restrict__ x,   const double* __restrict__ T,
    const double* __restrict__ Be, const float* __restrict__ w1,
    const float* __restrict__ b1,
    double* __restrict__ Qg, double* __restrict__ Pg)
{
    const int b  = blockIdx.y;
    const int s0 = blockIdx.x * 16;
    const int t  = threadIdx.x;
    const int lane = t & 63, wave = t >> 6;
    const int kq = wave & 3, ph = wave >> 2;

    __shared__ float  xl[CIN][37];
    __shared__ float  E[176 * 16];
    __shared__ double red[4][16][64];
    __shared__ double h[64 * 18];
    __shared__ int    COL[11];

    // conv weights (f64) into regs early — independent of LDS
    double wT[44];
    #pragma unroll
    for (int kk = 0; kk < 44; ++kk) wT[kk] = T[(kq*44+kk)*64 + lane];

    if (t < 11) { const int offs[11] = {-10,-5,-3,-2,-1,0,1,2,3,5,10}; COL[t] = offs[t] + 10; }
    for (int e = t; e < CIN * 36; e += 512) {
        int c = e / 36, col = e - c * 36;
        int g = s0 - 10 + col;
        xl[c][col] = (g >= 0 && g < SS) ? x[(b * CIN + c) * SS + g] : 0.f;
    }
    __syncthreads();                                       // S1: xl, COL
    for (int e = t; e < 2816; e += 512) {
        int k = e >> 4, p = e & 15;
        int c = k / 11, ti = k - c * 11;
        E[e] = xl[c][p + COL[ti]];
    }
    __syncthreads();                                       // S2: E ready

    double acc[8];
    #pragma unroll
    for (int q = 0; q < 8; ++q) acc[q] = 0.0;
    #pragma unroll 4
    for (int kk = 0; kk < 44; ++kk) {
        const float4* dp = (const float4*)(E + (kq*44+kk)*16 + ph*8);
        float4 v0 = dp[0], v1 = dp[1];
        double w = wT[kk];
        acc[0] += (double)v0.x * w; acc[1] += (double)v0.y * w;
        acc[2] += (double)v0.z * w; acc[3] += (double)v0.w * w;
        acc[4] += (double)v1.x * w; acc[5] += (double)v1.y * w;
        acc[6] += (double)v1.z * w; acc[7] += (double)v1.w * w;
    }

    // QP weights (f32 rows, per-lane gather; latency hides under reduction)
    double wq[16], wp[16];
    #pragma unroll
    for (int i = 0; i < 16; ++i) {
        wq[i] = (double)w1[lane*128 + kq*16 + i];
        wp[i] = (double)w1[lane*128 + 64 + kq*16 + i];
    }

    if (kq) { for (int q = 0; q < 8; ++q) red[kq][ph*8+q][lane] = acc[q]; }
    __syncthreads();                                       // S3
    if (!kq) {
        for (int q = 0; q < 8; ++q) {
            int p = ph*8 + q;
            double tot = acc[q] + red[1][p][lane] + red[2][p][lane] + red[3][p][lane]
                       + Be[(s0 + p) * 64 + lane];
            h[lane*18 + p] = tot > 0.0 ? tot : 0.0;
        }
    }
    __syncthreads();                                       // S4: h ready

    double aq[8], ap[8];
    #pragma unroll
    for (int q = 0; q < 8; ++q) { aq[q] = 0.0; ap[q] = 0.0; }
    #pragma unroll 4
    for (int kk = 0; kk < 16; ++kk) {
        int k = kq*16 + kk;
        const double2* hp = (const double2*)(h + k*18 + ph*8);
        double2 d0 = hp[0], d1 = hp[1], d2 = hp[2], d3 = hp[3];
        double q_ = wq[kk], p_ = wp[kk];
        aq[0] += d0.x*q_; ap[0] += d0.x*p_;  aq[1] += d0.y*q_; ap[1] += d0.y*p_;
        aq[2] += d1.x*q_; ap[2] += d1.x*p_;  aq[3] += d1.y*q_; ap[3] += d1.y*p_;
        aq[4] += d2.x*q_; ap[4] += d2.x*p_;  aq[5] += d2.y*q_; ap[5] += d2.y*p_;
        aq[6] += d3.x*q_; ap[6] += d3.x*p_;  aq[7] += d3.y*q_; ap[7] += d3.y*p_;
    }
    if (kq) { for (int q = 0; q < 8; ++q) red[kq][ph*8+q][lane] = aq[q]; }
    __syncthreads();                                       // S5
    if (!kq) {
        for (int q = 0; q < 8; ++q) {
            int p = ph*8 + q;
            Qg[((long)b*SS + s0 + p)*HH + lane] =
                aq[q] + red[1][p][lane] + red[2][p][lane] + red[3][p][lane];
        }
    }
    __syncthreads();                                       // S6
    if (kq) { for (int q = 0; q < 8; ++q) red[kq][ph*8+q][lane] = ap[q]; }
    __syncthreads();                                       // S7
    if (!kq) {
        double bv = (double)b1[lane];
        for (int q = 0; q < 8; ++q) {
            int p = ph*8 + q;
            Pg[((long)b*SS + s0 + p)*HH + lane] =
                ap[q] + red[1][p][lane] + red[2][p][lane] + red[3][p][lane] + bv;
        }
    }
}

// ---------------------------------------------------------------------------
// edges v3: 32x64 tiles, 8 edges/thread (2 i x 4 j). f32 screen via float4
// LDS reads + f64 exact recompute for |margin| < 2e-3 (rare, deterministic).
// ---------------------------------------------------------------------------
__global__ __launch_bounds__(256) void edges(
    const double* __restrict__ Qg, const double* __restrict__ Pg,
    const float* __restrict__ w2, const float* __restrict__ b2,
    const float* __restrict__ gum, float* __restrict__ out)
{
    const int b  = blockIdx.y;
    const int jt = blockIdx.x & 1, it = blockIdx.x >> 1;
    const int i0 = it * 32, j0 = jt * 64;
    const int t  = threadIdx.x;
    const int ti = t >> 4, tj = t & 15;

    if (j0 + 63 < i0) {                    // tile fully below diagonal
        for (int ii = 0; ii < 2; ++ii) {
            int i = i0 + ti*2 + ii;
            *(float4*)(out + ((long)b*SS + i)*SS + j0 + tj*4) = float4{0,0,0,0};
        }
        return;
    }

    __shared__ float Pl[32][68];
    __shared__ float Ql[64][68];
    __shared__ float dwl[64];

    if (t < 64) dwl[t] = w2[t] - w2[64 + t];
    for (int e = t; e < 2048; e += 256) {
        int r = e >> 6, c = e & 63;
        Pl[r][c] = (float)Pg[((long)b*SS + i0 + r)*HH + c];
    }
    for (int e = t; e < 4096; e += 256) {
        int r = e >> 6, c = e & 63;
        Ql[r][c] = (float)Qg[((long)b*SS + j0 + r)*HH + c];
    }
    __syncthreads();

    float a00=0,a01=0,a02=0,a03=0, a10=0,a11=0,a12=0,a13=0;
    const float4* P0 = (const float4*)&Pl[ti*2][0];
    const float4* P1 = (const float4*)&Pl[ti*2+1][0];
    const float4* Q0 = (const float4*)&Ql[tj*4][0];
    const float4* Q1 = (const float4*)&Ql[tj*4+1][0];
    const float4* Q2 = (const float4*)&Ql[tj*4+2][0];
    const float4* Q3 = (const float4*)&Ql[tj*4+3][0];
    const float4* DW = (const float4*)dwl;
#define RDOT(acc, pv, qv, dw) { float v; \
    v = pv.x + qv.x; v = v > 0.f ? v : 0.f; acc += v * dw.x; \
    v = pv.y + qv.y; v = v > 0.f ? v : 0.f; acc += v * dw.y; \
    v = pv.z + qv.z; v = v > 0.f ? v : 0.f; acc += v * dw.z; \
    v = pv.w + qv.w; v = v > 0.f ? v : 0.f; acc += v * dw.w; }
    #pragma unroll 4
    for (int k4 = 0; k4 < 16; ++k4) {
        float4 pv0 = P0[k4], pv1 = P1[k4], dw = DW[k4];
        float4 q0 = Q0[k4], q1 = Q1[k4], q2 = Q2[k4], q3 = Q3[k4];
        RDOT(a00, pv0, q0, dw) RDOT(a01, pv0, q1, dw)
        RDOT(a02, pv0, q2, dw) RDOT(a03, pv0, q3, dw)
        RDOT(a10, pv1, q0, dw) RDOT(a11, pv1, q1, dw)
        RDOT(a12, pv1, q2, dw) RDOT(a13, pv1, q3, dw)
    }
#undef RDOT
    const float db2 = b2[0] - b2[1];
    float accs[2][4] = {{a00,a01,a02,a03},{a10,a11,a12,a13}};
    for (int ii = 0; ii < 2; ++ii) {
        int i = i0 + ti*2 + ii;
        long e0 = (long)b*SS*SS + (long)i*SS + j0 + tj*4;
        float4 g01 = *(const float4*)(gum + e0*2);       // (u0,u1) for j, j+1
        float4 g23 = *(const float4*)(gum + e0*2 + 4);   // j+2, j+3
        float u0s[4] = {g01.x, g01.z, g23.x, g23.z};
        float u1s[4] = {g01.y, g01.w, g23.y, g23.w};
        float4 ov;
        float* ovp = (float*)&ov;
        for (int jj = 0; jj < 4; ++jj) {
            int j = j0 + tj*4 + jj;
            float r = 0.f;
            if (j > i) {
                float tot = db2 - logf(-logf(u0s[jj])) + logf(-logf(u1s[jj]))
                          + accs[ii][jj];
                if (fabsf(tot) < 2e-3f) {                 // exact f64 recompute
                    const double* Prd = Pg + ((long)b*SS + i)*HH;
                    const double* Qrd = Qg + ((long)b*SS + j)*HH;
                    double acc = (double)b2[0] - (double)b2[1]
                               - log(-log((double)u0s[jj]))
                               + log(-log((double)u1s[jj]));
                    for (int k = 0; k < 64; ++k) {
                        double v = Prd[k] + Qrd[k];
                        if (v > 0.0)
                            acc += v * ((double)w2[k] - (double)w2[64+k]);
                    }
                    r = (acc >= 0.0) ? 1.0f : 0.0f;
                } else {
                    r = (tot >= 0.f) ? 1.0f : 0.0f;
                }
            }
            ovp[jj] = r;
        }
        *(float4*)(out + ((long)b*SS + i)*SS + j0 + tj*4) = ov;
    }
}

extern "C" void kernel_launch(void* const* d_in, const int* in_sizes, int n_in,
                              void* d_out, int out_size, void* d_ws, size_t ws_size,
                              hipStream_t stream) {
    const float* data = (const float*)d_in[0];
    const float* w11  = (const float*)d_in[1];
    const float* b11  = (const float*)d_in[2];
    const float* w12  = (const float*)d_in[3];
    const float* b12  = (const float*)d_in[4];
    const float* w21  = (const float*)d_in[5];
    const float* b21  = (const float*)d_in[6];
    const float* w22  = (const float*)d_in[7];
    const float* b22  = (const float*)d_in[8];
    const float* w31  = (const float*)d_in[9];
    const float* b31  = (const float*)d_in[10];
    const float* wf   = (const float*)d_in[11];
    const float* bf   = (const float*)d_in[12];
    const float* w1   = (const float*)d_in[13];
    const float* b1   = (const float*)d_in[14];
    const float* w2   = (const float*)d_in[15];
    const float* b2   = (const float*)d_in[16];
    const float* gum  = (const float*)d_in[17];
    float* out = (float*)d_out;

    double* Qg  = (double*)d_ws;            // 262144
    double* Pg  = Qg  + 262144;             // 262144
    double* T   = Pg  + 262144;             // 11264
    double* Be  = T   + 11264;              // 8192
    double* W1e = Be  + 8192;               // 3072
    double* W2e = W1e + 3072;               // 5120
    double* SW1 = W2e + 5120;               // 192
    double* SW2 = SW1 + 192;                // 320  (total ~4.42 MB)

    prep1<<<34, 256, 0, stream>>>(w11, w21, w12, w22, b11, b21, W1e, W2e, SW1, SW2);
    prep2<<<76, 256, 0, stream>>>(wf, bf, b12, b22, b31, w31, W1e, W2e, SW1, SW2, T, Be);
    front<<<dim3(8, BB), 512, 0, stream>>>(data, T, Be, w1, b1, Qg, Pg);
    edges<<<dim3(8, BB), 256, 0, stream>>>(Qg, Pg, w2, b2, gum, out);
}

// Round 12
// 79.899 us; speedup vs baseline: 1.7532x; 1.7532x over previous
//
#include <hip/hip_runtime.h>
#include <math.h>

#define BB   32
#define CIN  16
#define HH   64
#define SS   128

// ---------------------------------------------------------------------------
// Composite-weight front-end (R11-verified math):
//   h_pre[n][p] = sum_{c,ti} T[n][c][ti]*xpad[c][p+off(ti)] + B_eff[n][p]
//   taps off(ti), ti=0..10: {-10,-5,-3,-2,-1,0,1,2,3,5,10}
//   x1 (w12 o w11): ti {2,5,8}; x2 (w22 o w21): ti {0,1,5,9,10}; x3: ti {3..7}
// All composites in f64. R11 regression was rule-#20 scratch spill (partial
// unroll -> runtime-indexed register arrays) + gather-heavy prep2; fixed here.
// ---------------------------------------------------------------------------

// prep1: W1e[m][c][t], W2e[m][c][u], wfT[m][n]=wf[n][m] (f64),
//        b1e[m][p] = b12[m] + sum_{t in range} sum_mm w12[m][mm][t]*b11[mm]
//        b2e[m][p] likewise (5 taps).
__global__ __launch_bounds__(256) void prep1(
    const float* __restrict__ w11, const float* __restrict__ w21,
    const float* __restrict__ w12, const float* __restrict__ w22,
    const float* __restrict__ b11, const float* __restrict__ b21,
    const float* __restrict__ b12, const float* __restrict__ b22,
    const float* __restrict__ wf,
    double* __restrict__ W1e, double* __restrict__ W2e,
    double* __restrict__ wfT, double* __restrict__ b1e,
    double* __restrict__ b2e)
{
    int o = blockIdx.x * 256 + threadIdx.x;
    if (o < 3072) {
        int m = o / 48, r = o % 48, c = r / 3, t = r % 3;
        double a0 = 0, a1 = 0;
        #pragma unroll
        for (int mm = 0; mm < 64; mm += 2) {
            a0 += (double)w12[(m*64+mm)*3+t]   * (double)w11[mm*16+c];
            a1 += (double)w12[(m*64+mm+1)*3+t] * (double)w11[(mm+1)*16+c];
        }
        W1e[o] = a0 + a1;
    } else if (o < 8192) {
        int j = o - 3072;
        int m = j / 80, r = j % 80, c = r / 5, u = r % 5;
        double a0 = 0, a1 = 0;
        #pragma unroll
        for (int mm = 0; mm < 64; mm += 2) {
            a0 += (double)w22[(m*64+mm)*5+u]   * (double)w21[mm*16+c];
            a1 += (double)w22[(m*64+mm+1)*5+u] * (double)w21[(mm+1)*16+c];
        }
        W2e[j] = a0 + a1;
    } else if (o < 20480) {
        int j = o - 8192;                      // wfT[m*64+n] = wf[n*192+m]
        wfT[j] = (double)wf[(j & 63) * 192 + (j >> 6)];
    } else if (o < 28672) {
        int j = o - 20480; int m = j >> 7, p = j & 127;
        double a = (double)b12[m];
        #pragma unroll
        for (int t = 0; t < 3; ++t) {
            int pos = p + (t - 1) * 3;
            if (pos >= 0 && pos < SS) {
                double s0 = 0, s1 = 0;
                #pragma unroll
                for (int mm = 0; mm < 64; mm += 2) {
                    s0 += (double)w12[(m*64+mm)*3+t]   * (double)b11[mm];
                    s1 += (double)w12[(m*64+mm+1)*3+t] * (double)b11[mm+1];
                }
                a += s0 + s1;
            }
        }
        b1e[j] = a;
    } else if (o < 36864) {
        int j = o - 28672; int m = j >> 7, p = j & 127;
        double a = (double)b22[m];
        #pragma unroll
        for (int u = 0; u < 5; ++u) {
            int pos = p + (u - 2) * 5;
            if (pos >= 0 && pos < SS) {
                double s0 = 0, s1 = 0;
                #pragma unroll
                for (int mm = 0; mm < 64; mm += 2) {
                    s0 += (double)w22[(m*64+mm)*5+u]   * (double)b21[mm];
                    s1 += (double)w22[(m*64+mm+1)*5+u] * (double)b21[mm+1];
                }
                a += s0 + s1;
            }
        }
        b2e[j] = a;
    }
}

// prep2: T[(c*11+ti)*64+n] (lane-coalesced via wfT), Be[p*64+n].
__global__ __launch_bounds__(256) void prep2(
    const float* __restrict__ bf,  const float* __restrict__ b31,
    const float* __restrict__ w31,
    const double* __restrict__ W1e, const double* __restrict__ W2e,
    const double* __restrict__ wfT, const double* __restrict__ b1e,
    const double* __restrict__ b2e,
    double* __restrict__ T, double* __restrict__ Be)
{
    int o = blockIdx.x * 256 + threadIdx.x;
    if (o < 11264) {
        int n = o & 63, k = o >> 6, c = k / 11, ti = k % 11;
        double a0 = 0, a1 = 0;
        if (ti == 2 || ti == 5 || ti == 8) {
            int t = (ti - 2) / 3;
            #pragma unroll
            for (int m = 0; m < 64; m += 2) {
                a0 += wfT[m*64+n]     * W1e[m*48 + c*3 + t];
                a1 += wfT[(m+1)*64+n] * W1e[(m+1)*48 + c*3 + t];
            }
        }
        if (ti == 0 || ti == 1 || ti == 5 || ti == 9 || ti == 10) {
            int u = (ti == 0) ? 0 : (ti == 1) ? 1 : (ti == 5) ? 2 : (ti == 9) ? 3 : 4;
            #pragma unroll
            for (int m = 0; m < 64; m += 2) {
                a0 += wfT[(64+m)*64+n]   * W2e[m*80 + c*5 + u];
                a1 += wfT[(64+m+1)*64+n] * W2e[(m+1)*80 + c*5 + u];
            }
        }
        if (ti >= 3 && ti <= 7) {
            int v = ti - 3;
            #pragma unroll
            for (int m = 0; m < 64; m += 2) {
                a0 += wfT[(128+m)*64+n]   * (double)w31[(m*16+c)*5+v];
                a1 += wfT[(128+m+1)*64+n] * (double)w31[((m+1)*16+c)*5+v];
            }
        }
        T[k*64+n] = a0 + a1;
    } else if (o < 19456) {
        int j = o - 11264; int n = j & 63, p = j >> 6;
        double a0 = (double)bf[n], a1 = 0, a2 = 0;
        #pragma unroll
        for (int m = 0; m < 64; ++m) {
            a0 += wfT[m*64+n]       * b1e[m*128+p];
            a1 += wfT[(64+m)*64+n]  * b2e[m*128+p];
            a2 += wfT[(128+m)*64+n] * (double)b31[m];
        }
        Be[p*64+n] = a0 + a1 + a2;
    }
}

// ---------------------------------------------------------------------------
// front: 512 thr = 8 waves = (kq 0..3) x (ph 0..1). lane = channel n.
// FULL unroll everywhere -> weight arrays stay in registers (rule #20 fix).
// Conv/QP LDS reads are wave-uniform broadcasts; reductions lane-coalesced.
// ---------------------------------------------------------------------------
__global__ __launch_bounds__(512, 1) void front(
    const float* __restrict__ x,   const double* __restrict__ T,
    const double* __restrict__ Be, const float* __restrict__ w1,
    const float* __restrict__ b1,
    double* __restrict__ Qg, double* __restrict__ Pg)
{
    const int b  = blockIdx.y;
    const int s0 = blockIdx.x * 16;
    const int t  = threadIdx.x;
    const int lane = t & 63, wave = t >> 6;
    const int kq = wave & 3, ph = wave >> 2;

    __shared__ float  xl[CIN][37];
    __shared__ float  E[176 * 16];
    __shared__ double red[4][16][64];
    __shared__ double h[64 * 18];
    __shared__ int    COL[11];

    double wT[44];
    #pragma unroll
    for (int kk = 0; kk < 44; ++kk) wT[kk] = T[(kq*44+kk)*64 + lane];

    if (t < 11) { const int offs[11] = {-10,-5,-3,-2,-1,0,1,2,3,5,10}; COL[t] = offs[t] + 10; }
    for (int e = t; e < CIN * 36; e += 512) {
        int c = e / 36, col = e - c * 36;
        int g = s0 - 10 + col;
        xl[c][col] = (g >= 0 && g < SS) ? x[(b * CIN + c) * SS + g] : 0.f;
    }
    __syncthreads();                                       // S1
    for (int e = t; e < 2816; e += 512) {
        int k = e >> 4, p = e & 15;
        int c = k / 11, ti = k - c * 11;
        E[e] = xl[c][p + COL[ti]];
    }
    __syncthreads();                                       // S2

    double acc[8];
    #pragma unroll
    for (int q = 0; q < 8; ++q) acc[q] = 0.0;
    #pragma unroll
    for (int kk = 0; kk < 44; ++kk) {
        const float4* dp = (const float4*)(E + (kq*44+kk)*16 + ph*8);
        float4 v0 = dp[0], v1 = dp[1];
        double w = wT[kk];
        acc[0] += (double)v0.x * w; acc[1] += (double)v0.y * w;
        acc[2] += (double)v0.z * w; acc[3] += (double)v0.w * w;
        acc[4] += (double)v1.x * w; acc[5] += (double)v1.y * w;
        acc[6] += (double)v1.z * w; acc[7] += (double)v1.w * w;
    }

    double wq[16], wp[16];
    #pragma unroll
    for (int i = 0; i < 16; ++i) {
        wq[i] = (double)w1[lane*128 + kq*16 + i];
        wp[i] = (double)w1[lane*128 + 64 + kq*16 + i];
    }

    if (kq) { for (int q = 0; q < 8; ++q) red[kq][ph*8+q][lane] = acc[q]; }
    __syncthreads();                                       // S3
    if (!kq) {
        for (int q = 0; q < 8; ++q) {
            int p = ph*8 + q;
            double tot = acc[q] + red[1][p][lane] + red[2][p][lane] + red[3][p][lane]
                       + Be[(s0 + p) * 64 + lane];
            h[lane*18 + p] = tot > 0.0 ? tot : 0.0;
        }
    }
    __syncthreads();                                       // S4

    double aq[8], ap[8];
    #pragma unroll
    for (int q = 0; q < 8; ++q) { aq[q] = 0.0; ap[q] = 0.0; }
    #pragma unroll
    for (int kk = 0; kk < 16; ++kk) {
        int k = kq*16 + kk;
        const double2* hp = (const double2*)(h + k*18 + ph*8);
        double2 d0 = hp[0], d1 = hp[1], d2 = hp[2], d3 = hp[3];
        double q_ = wq[kk], p_ = wp[kk];
        aq[0] += d0.x*q_; ap[0] += d0.x*p_;  aq[1] += d0.y*q_; ap[1] += d0.y*p_;
        aq[2] += d1.x*q_; ap[2] += d1.x*p_;  aq[3] += d1.y*q_; ap[3] += d1.y*p_;
        aq[4] += d2.x*q_; ap[4] += d2.x*p_;  aq[5] += d2.y*q_; ap[5] += d2.y*p_;
        aq[6] += d3.x*q_; ap[6] += d3.x*p_;  aq[7] += d3.y*q_; ap[7] += d3.y*p_;
    }
    if (kq) { for (int q = 0; q < 8; ++q) red[kq][ph*8+q][lane] = aq[q]; }
    __syncthreads();                                       // S5
    if (!kq) {
        for (int q = 0; q < 8; ++q) {
            int p = ph*8 + q;
            Qg[((long)b*SS + s0 + p)*HH + lane] =
                aq[q] + red[1][p][lane] + red[2][p][lane] + red[3][p][lane];
        }
    }
    __syncthreads();                                       // S6
    if (kq) { for (int q = 0; q < 8; ++q) red[kq][ph*8+q][lane] = ap[q]; }
    __syncthreads();                                       // S7
    if (!kq) {
        double bv = (double)b1[lane];
        for (int q = 0; q < 8; ++q) {
            int p = ph*8 + q;
            Pg[((long)b*SS + s0 + p)*HH + lane] =
                ap[q] + red[1][p][lane] + red[2][p][lane] + red[3][p][lane] + bv;
        }
    }
}

// ---------------------------------------------------------------------------
// edges (R11-identical, known-good): 32x64 tiles, 8 edges/thread, f32 screen
// + f64 exact recompute for |margin| < 2e-3.
// ---------------------------------------------------------------------------
__global__ __launch_bounds__(256) void edges(
    const double* __restrict__ Qg, const double* __restrict__ Pg,
    const float* __restrict__ w2, const float* __restrict__ b2,
    const float* __restrict__ gum, float* __restrict__ out)
{
    const int b  = blockIdx.y;
    const int jt = blockIdx.x & 1, it = blockIdx.x >> 1;
    const int i0 = it * 32, j0 = jt * 64;
    const int t  = threadIdx.x;
    const int ti = t >> 4, tj = t & 15;

    if (j0 + 63 < i0) {
        for (int ii = 0; ii < 2; ++ii) {
            int i = i0 + ti*2 + ii;
            *(float4*)(out + ((long)b*SS + i)*SS + j0 + tj*4) = float4{0,0,0,0};
        }
        return;
    }

    __shared__ float Pl[32][68];
    __shared__ float Ql[64][68];
    __shared__ float dwl[64];

    if (t < 64) dwl[t] = w2[t] - w2[64 + t];
    for (int e = t; e < 2048; e += 256) {
        int r = e >> 6, c = e & 63;
        Pl[r][c] = (float)Pg[((long)b*SS + i0 + r)*HH + c];
    }
    for (int e = t; e < 4096; e += 256) {
        int r = e >> 6, c = e & 63;
        Ql[r][c] = (float)Qg[((long)b*SS + j0 + r)*HH + c];
    }
    __syncthreads();

    float a00=0,a01=0,a02=0,a03=0, a10=0,a11=0,a12=0,a13=0;
    const float4* P0 = (const float4*)&Pl[ti*2][0];
    const float4* P1 = (const float4*)&Pl[ti*2+1][0];
    const float4* Q0 = (const float4*)&Ql[tj*4][0];
    const float4* Q1 = (const float4*)&Ql[tj*4+1][0];
    const float4* Q2 = (const float4*)&Ql[tj*4+2][0];
    const float4* Q3 = (const float4*)&Ql[tj*4+3][0];
    const float4* DW = (const float4*)dwl;
#define RDOT(acc, pv, qv, dw) { float v; \
    v = pv.x + qv.x; v = v > 0.f ? v : 0.f; acc += v * dw.x; \
    v = pv.y + qv.y; v = v > 0.f ? v : 0.f; acc += v * dw.y; \
    v = pv.z + qv.z; v = v > 0.f ? v : 0.f; acc += v * dw.z; \
    v = pv.w + qv.w; v = v > 0.f ? v : 0.f; acc += v * dw.w; }
    #pragma unroll 4
    for (int k4 = 0; k4 < 16; ++k4) {
        float4 pv0 = P0[k4], pv1 = P1[k4], dw = DW[k4];
        float4 q0 = Q0[k4], q1 = Q1[k4], q2 = Q2[k4], q3 = Q3[k4];
        RDOT(a00, pv0, q0, dw) RDOT(a01, pv0, q1, dw)
        RDOT(a02, pv0, q2, dw) RDOT(a03, pv0, q3, dw)
        RDOT(a10, pv1, q0, dw) RDOT(a11, pv1, q1, dw)
        RDOT(a12, pv1, q2, dw) RDOT(a13, pv1, q3, dw)
    }
#undef RDOT
    const float db2 = b2[0] - b2[1];
    float accs[2][4] = {{a00,a01,a02,a03},{a10,a11,a12,a13}};
    for (int ii = 0; ii < 2; ++ii) {
        int i = i0 + ti*2 + ii;
        long e0 = (long)b*SS*SS + (long)i*SS + j0 + tj*4;
        float4 g01 = *(const float4*)(gum + e0*2);
        float4 g23 = *(const float4*)(gum + e0*2 + 4);
        float u0s[4] = {g01.x, g01.z, g23.x, g23.z};
        float u1s[4] = {g01.y, g01.w, g23.y, g23.w};
        float4 ov;
        float* ovp = (float*)&ov;
        for (int jj = 0; jj < 4; ++jj) {
            int j = j0 + tj*4 + jj;
            float r = 0.f;
            if (j > i) {
                float tot = db2 - logf(-logf(u0s[jj])) + logf(-logf(u1s[jj]))
                          + accs[ii][jj];
                if (fabsf(tot) < 2e-3f) {
                    const double* Prd = Pg + ((long)b*SS + i)*HH;
                    const double* Qrd = Qg + ((long)b*SS + j)*HH;
                    double acc = (double)b2[0] - (double)b2[1]
                               - log(-log((double)u0s[jj]))
                               + log(-log((double)u1s[jj]));
                    for (int k = 0; k < 64; ++k) {
                        double v = Prd[k] + Qrd[k];
                        if (v > 0.0)
                            acc += v * ((double)w2[k] - (double)w2[64+k]);
                    }
                    r = (acc >= 0.0) ? 1.0f : 0.0f;
                } else {
                    r = (tot >= 0.f) ? 1.0f : 0.0f;
                }
            }
            ovp[jj] = r;
        }
        *(float4*)(out + ((long)b*SS + i)*SS + j0 + tj*4) = ov;
    }
}

extern "C" void kernel_launch(void* const* d_in, const int* in_sizes, int n_in,
                              void* d_out, int out_size, void* d_ws, size_t ws_size,
                              hipStream_t stream) {
    const float* data = (const float*)d_in[0];
    const float* w11  = (const float*)d_in[1];
    const float* b11  = (const float*)d_in[2];
    const float* w12  = (const float*)d_in[3];
    const float* b12  = (const float*)d_in[4];
    const float* w21  = (const float*)d_in[5];
    const float* b21  = (const float*)d_in[6];
    const float* w22  = (const float*)d_in[7];
    const float* b22  = (const float*)d_in[8];
    const float* w31  = (const float*)d_in[9];
    const float* b31  = (const float*)d_in[10];
    const float* wf   = (const float*)d_in[11];
    const float* bf   = (const float*)d_in[12];
    const float* w1   = (const float*)d_in[13];
    const float* b1   = (const float*)d_in[14];
    const float* w2   = (const float*)d_in[15];
    const float* b2   = (const float*)d_in[16];
    const float* gum  = (const float*)d_in[17];
    float* out = (float*)d_out;

    // ws layout (doubles): T, Be persistent; Qg/Pg written by front;
    // prep intermediates OVERLAY Qg region (dead before front runs).
    double* T   = (double*)d_ws;            // 11264
    double* Be  = T   + 11264;              // 8192
    double* Qg  = Be  + 8192;               // 262144
    double* Pg  = Qg  + 262144;             // 262144  (total 4.35 MB)
    double* W1e = Qg;                       // 3072   (overlay)
    double* W2e = W1e + 3072;               // 5120
    double* wfT = W2e + 5120;               // 12288
    double* b1e = wfT + 12288;              // 8192
    double* b2e = b1e + 8192;               // 8192   (36864 < 262144 ✓)

    prep1<<<144, 256, 0, stream>>>(w11, w21, w12, w22, b11, b21, b12, b22, wf,
                                   W1e, W2e, wfT, b1e, b2e);
    prep2<<<76, 256, 0, stream>>>(bf, b31, w31, W1e, W2e, wfT, b1e, b2e, T, Be);
    front<<<dim3(8, BB), 512, 0, stream>>>(data, T, Be, w1, b1, Qg, Pg);
    edges<<<dim3(8, BB), 256, 0, stream>>>(Qg, Pg, w2, b2, gum, out);
}

// Round 13
// 73.343 us; speedup vs baseline: 1.9099x; 1.0894x over previous
//
#include <hip/hip_runtime.h>
#include <math.h>

#define BB   32
#define CIN  16
#define HH   64
#define SS   128

// ---------------------------------------------------------------------------
// Composite-weight front-end (R11/R12-verified math):
//   h_pre[n][p] = sum_{c,ti} T[n][c][ti]*xpad[c][p+off(ti)] + B_eff[n][p]
//   taps off(ti), ti=0..10: {-10,-5,-3,-2,-1,0,1,2,3,5,10}
// ---------------------------------------------------------------------------

// prep1 (R12-identical)
__global__ __launch_bounds__(256) void prep1(
    const float* __restrict__ w11, const float* __restrict__ w21,
    const float* __restrict__ w12, const float* __restrict__ w22,
    const float* __restrict__ b11, const float* __restrict__ b21,
    const float* __restrict__ b12, const float* __restrict__ b22,
    const float* __restrict__ wf,
    double* __restrict__ W1e, double* __restrict__ W2e,
    double* __restrict__ wfT, double* __restrict__ b1e,
    double* __restrict__ b2e)
{
    int o = blockIdx.x * 256 + threadIdx.x;
    if (o < 3072) {
        int m = o / 48, r = o % 48, c = r / 3, t = r % 3;
        double a0 = 0, a1 = 0;
        #pragma unroll
        for (int mm = 0; mm < 64; mm += 2) {
            a0 += (double)w12[(m*64+mm)*3+t]   * (double)w11[mm*16+c];
            a1 += (double)w12[(m*64+mm+1)*3+t] * (double)w11[(mm+1)*16+c];
        }
        W1e[o] = a0 + a1;
    } else if (o < 8192) {
        int j = o - 3072;
        int m = j / 80, r = j % 80, c = r / 5, u = r % 5;
        double a0 = 0, a1 = 0;
        #pragma unroll
        for (int mm = 0; mm < 64; mm += 2) {
            a0 += (double)w22[(m*64+mm)*5+u]   * (double)w21[mm*16+c];
            a1 += (double)w22[(m*64+mm+1)*5+u] * (double)w21[(mm+1)*16+c];
        }
        W2e[j] = a0 + a1;
    } else if (o < 20480) {
        int j = o - 8192;
        wfT[j] = (double)wf[(j & 63) * 192 + (j >> 6)];
    } else if (o < 28672) {
        int j = o - 20480; int m = j >> 7, p = j & 127;
        double a = (double)b12[m];
        #pragma unroll
        for (int t = 0; t < 3; ++t) {
            int pos = p + (t - 1) * 3;
            if (pos >= 0 && pos < SS) {
                double s0 = 0, s1 = 0;
                #pragma unroll
                for (int mm = 0; mm < 64; mm += 2) {
                    s0 += (double)w12[(m*64+mm)*3+t]   * (double)b11[mm];
                    s1 += (double)w12[(m*64+mm+1)*3+t] * (double)b11[mm+1];
                }
                a += s0 + s1;
            }
        }
        b1e[j] = a;
    } else if (o < 36864) {
        int j = o - 28672; int m = j >> 7, p = j & 127;
        double a = (double)b22[m];
        #pragma unroll
        for (int u = 0; u < 5; ++u) {
            int pos = p + (u - 2) * 5;
            if (pos >= 0 && pos < SS) {
                double s0 = 0, s1 = 0;
                #pragma unroll
                for (int mm = 0; mm < 64; mm += 2) {
                    s0 += (double)w22[(m*64+mm)*5+u]   * (double)b21[mm];
                    s1 += (double)w22[(m*64+mm+1)*5+u] * (double)b21[mm+1];
                }
                a += s0 + s1;
            }
        }
        b2e[j] = a;
    }
}

// prep2 (R12-identical)
__global__ __launch_bounds__(256) void prep2(
    const float* __restrict__ bf,  const float* __restrict__ b31,
    const float* __restrict__ w31,
    const double* __restrict__ W1e, const double* __restrict__ W2e,
    const double* __restrict__ wfT, const double* __restrict__ b1e,
    const double* __restrict__ b2e,
    double* __restrict__ T, double* __restrict__ Be)
{
    int o = blockIdx.x * 256 + threadIdx.x;
    if (o < 11264) {
        int n = o & 63, k = o >> 6, c = k / 11, ti = k % 11;
        double a0 = 0, a1 = 0;
        if (ti == 2 || ti == 5 || ti == 8) {
            int t = (ti - 2) / 3;
            #pragma unroll
            for (int m = 0; m < 64; m += 2) {
                a0 += wfT[m*64+n]     * W1e[m*48 + c*3 + t];
                a1 += wfT[(m+1)*64+n] * W1e[(m+1)*48 + c*3 + t];
            }
        }
        if (ti == 0 || ti == 1 || ti == 5 || ti == 9 || ti == 10) {
            int u = (ti == 0) ? 0 : (ti == 1) ? 1 : (ti == 5) ? 2 : (ti == 9) ? 3 : 4;
            #pragma unroll
            for (int m = 0; m < 64; m += 2) {
                a0 += wfT[(64+m)*64+n]   * W2e[m*80 + c*5 + u];
                a1 += wfT[(64+m+1)*64+n] * W2e[(m+1)*80 + c*5 + u];
            }
        }
        if (ti >= 3 && ti <= 7) {
            int v = ti - 3;
            #pragma unroll
            for (int m = 0; m < 64; m += 2) {
                a0 += wfT[(128+m)*64+n]   * (double)w31[(m*16+c)*5+v];
                a1 += wfT[(128+m+1)*64+n] * (double)w31[((m+1)*16+c)*5+v];
            }
        }
        T[k*64+n] = a0 + a1;
    } else if (o < 19456) {
        int j = o - 11264; int n = j & 63, p = j >> 6;
        double a0 = (double)bf[n], a1 = 0, a2 = 0;
        #pragma unroll
        for (int m = 0; m < 64; ++m) {
            a0 += wfT[m*64+n]       * b1e[m*128+p];
            a1 += wfT[(64+m)*64+n]  * b2e[m*128+p];
            a2 += wfT[(128+m)*64+n] * (double)b31[m];
        }
        Be[p*64+n] = a0 + a1 + a2;
    }
}

// ---------------------------------------------------------------------------
// front v3: 512 thr = 8 waves = (kq 0..3) x (ph 0..1). lane = channel n.
// Register diet: only wT[44] f64 lives in regs; w1 staged in LDS (padded 65,
// 2-way reads = free). Q/P reductions share one barrier via red/redP.
// Peak regs ~134 -> no spill possible.
// ---------------------------------------------------------------------------
__global__ __launch_bounds__(512, 1) void front(
    const float* __restrict__ x,   const double* __restrict__ T,
    const double* __restrict__ Be, const float* __restrict__ w1,
    const float* __restrict__ b1,
    double* __restrict__ Qg, double* __restrict__ Pg)
{
    const int b  = blockIdx.y;
    const int s0 = blockIdx.x * 16;
    const int t  = threadIdx.x;
    const int lane = t & 63, wave = t >> 6;
    const int kq = wave & 3, ph = wave >> 2;

    __shared__ float  xl[CIN][37];
    __shared__ float  E[176 * 16];
    __shared__ float  w1L[128 * 65];        // w1L[k*65+n] = w1[n*128+k]
    __shared__ double red [4][16][64];
    __shared__ double redP[4][16][64];
    __shared__ double h[64 * 18];
    __shared__ int    COL[11];

    double wT[44];
    #pragma unroll
    for (int kk = 0; kk < 44; ++kk) wT[kk] = T[(kq*44+kk)*64 + lane];

    if (t < 11) { const int offs[11] = {-10,-5,-3,-2,-1,0,1,2,3,5,10}; COL[t] = offs[t] + 10; }
    for (int e = t; e < CIN * 36; e += 512) {
        int c = e / 36, col = e - c * 36;
        int g = s0 - 10 + col;
        xl[c][col] = (g >= 0 && g < SS) ? x[(b * CIN + c) * SS + g] : 0.f;
    }
    for (int e = t; e < 8192; e += 512) {     // stage w1 transposed
        int n = e >> 7, k = e & 127;
        w1L[k * 65 + n] = w1[e];
    }
    __syncthreads();                                       // S1
    for (int e = t; e < 2816; e += 512) {
        int k = e >> 4, p = e & 15;
        int c = k / 11, ti = k - c * 11;
        E[e] = xl[c][p + COL[ti]];
    }
    __syncthreads();                                       // S2

    double acc[8];
    #pragma unroll
    for (int q = 0; q < 8; ++q) acc[q] = 0.0;
    #pragma unroll
    for (int kk = 0; kk < 44; ++kk) {
        const float4* dp = (const float4*)(E + (kq*44+kk)*16 + ph*8);
        float4 v0 = dp[0], v1 = dp[1];
        double w = wT[kk];
        acc[0] += (double)v0.x * w; acc[1] += (double)v0.y * w;
        acc[2] += (double)v0.z * w; acc[3] += (double)v0.w * w;
        acc[4] += (double)v1.x * w; acc[5] += (double)v1.y * w;
        acc[6] += (double)v1.z * w; acc[7] += (double)v1.w * w;
    }
    if (kq) { for (int q = 0; q < 8; ++q) red[kq][ph*8+q][lane] = acc[q]; }
    __syncthreads();                                       // S3
    if (!kq) {
        for (int q = 0; q < 8; ++q) {
            int p = ph*8 + q;
            double tot = acc[q] + red[1][p][lane] + red[2][p][lane] + red[3][p][lane]
                       + Be[(s0 + p) * 64 + lane];
            h[lane*18 + p] = tot > 0.0 ? tot : 0.0;
        }
    }
    __syncthreads();                                       // S4

    double aq[8], ap[8];
    #pragma unroll
    for (int q = 0; q < 8; ++q) { aq[q] = 0.0; ap[q] = 0.0; }
    #pragma unroll
    for (int kk = 0; kk < 16; ++kk) {
        int k = kq*16 + kk;
        double q_ = (double)w1L[k * 65 + lane];
        double p_ = (double)w1L[(64 + k) * 65 + lane];
        const double2* hp = (const double2*)(h + k*18 + ph*8);
        double2 d0 = hp[0], d1 = hp[1], d2 = hp[2], d3 = hp[3];
        aq[0] += d0.x*q_; ap[0] += d0.x*p_;  aq[1] += d0.y*q_; ap[1] += d0.y*p_;
        aq[2] += d1.x*q_; ap[2] += d1.x*p_;  aq[3] += d1.y*q_; ap[3] += d1.y*p_;
        aq[4] += d2.x*q_; ap[4] += d2.x*p_;  aq[5] += d2.y*q_; ap[5] += d2.y*p_;
        aq[6] += d3.x*q_; ap[6] += d3.x*p_;  aq[7] += d3.y*q_; ap[7] += d3.y*p_;
    }
    if (kq) {
        for (int q = 0; q < 8; ++q) {
            red [kq][ph*8+q][lane] = aq[q];
            redP[kq][ph*8+q][lane] = ap[q];
        }
    }
    __syncthreads();                                       // S5
    if (!kq) {
        double bv = (double)b1[lane];
        for (int q = 0; q < 8; ++q) {
            int p = ph*8 + q;
            Qg[((long)b*SS + s0 + p)*HH + lane] =
                aq[q] + red[1][p][lane] + red[2][p][lane] + red[3][p][lane];
            Pg[((long)b*SS + s0 + p)*HH + lane] =
                ap[q] + redP[1][p][lane] + redP[2][p][lane] + redP[3][p][lane] + bv;
        }
    }
}

// ---------------------------------------------------------------------------
// edges v4: 32x64 tiles, 8 edges/thread with j = j0 + tj + 16*jj (Q row
// stride 1 across lanes -> 2-way banks, free; old tj*4 mapping was 8-way).
// f32 screen + f64 exact recompute for |margin| < 2e-3.
// ---------------------------------------------------------------------------
__global__ __launch_bounds__(256) void edges(
    const double* __restrict__ Qg, const double* __restrict__ Pg,
    const float* __restrict__ w2, const float* __restrict__ b2,
    const float* __restrict__ gum, float* __restrict__ out)
{
    const int b  = blockIdx.y;
    const int jt = blockIdx.x & 1, it = blockIdx.x >> 1;
    const int i0 = it * 32, j0 = jt * 64;
    const int t  = threadIdx.x;
    const int ti = t >> 4, tj = t & 15;

    if (j0 + 63 < i0) {
        for (int ii = 0; ii < 2; ++ii) {
            int i = i0 + ti*2 + ii;
            *(float4*)(out + ((long)b*SS + i)*SS + j0 + tj*4) = float4{0,0,0,0};
        }
        return;
    }

    __shared__ float Pl[32][68];
    __shared__ float Ql[64][68];
    __shared__ float dwl[64];

    if (t < 64) dwl[t] = w2[t] - w2[64 + t];
    for (int e = t; e < 2048; e += 256) {
        int r = e >> 6, c = e & 63;
        Pl[r][c] = (float)Pg[((long)b*SS + i0 + r)*HH + c];
    }
    for (int e = t; e < 4096; e += 256) {
        int r = e >> 6, c = e & 63;
        Ql[r][c] = (float)Qg[((long)b*SS + j0 + r)*HH + c];
    }
    __syncthreads();

    float a00=0,a01=0,a02=0,a03=0, a10=0,a11=0,a12=0,a13=0;
    const float4* P0 = (const float4*)&Pl[ti*2][0];
    const float4* P1 = (const float4*)&Pl[ti*2+1][0];
    const float4* Q0 = (const float4*)&Ql[tj][0];
    const float4* Q1 = (const float4*)&Ql[tj+16][0];
    const float4* Q2 = (const float4*)&Ql[tj+32][0];
    const float4* Q3 = (const float4*)&Ql[tj+48][0];
    const float4* DW = (const float4*)dwl;
#define RDOT(acc, pv, qv, dw) { float v; \
    v = pv.x + qv.x; v = v > 0.f ? v : 0.f; acc += v * dw.x; \
    v = pv.y + qv.y; v = v > 0.f ? v : 0.f; acc += v * dw.y; \
    v = pv.z + qv.z; v = v > 0.f ? v : 0.f; acc += v * dw.z; \
    v = pv.w + qv.w; v = v > 0.f ? v : 0.f; acc += v * dw.w; }
    #pragma unroll 4
    for (int k4 = 0; k4 < 16; ++k4) {
        float4 pv0 = P0[k4], pv1 = P1[k4], dw = DW[k4];
        float4 q0 = Q0[k4], q1 = Q1[k4], q2 = Q2[k4], q3 = Q3[k4];
        RDOT(a00, pv0, q0, dw) RDOT(a01, pv0, q1, dw)
        RDOT(a02, pv0, q2, dw) RDOT(a03, pv0, q3, dw)
        RDOT(a10, pv1, q0, dw) RDOT(a11, pv1, q1, dw)
        RDOT(a12, pv1, q2, dw) RDOT(a13, pv1, q3, dw)
    }
#undef RDOT
    const float db2 = b2[0] - b2[1];
    float accs[2][4] = {{a00,a01,a02,a03},{a10,a11,a12,a13}};
    for (int ii = 0; ii < 2; ++ii) {
        int i = i0 + ti*2 + ii;
        for (int jj = 0; jj < 4; ++jj) {
            int j = j0 + tj + 16*jj;
            float r = 0.f;
            if (j > i) {
                long e = (long)b*SS*SS + (long)i*SS + j;
                float2 uv = *(const float2*)(gum + e*2);
                float tot = db2 - logf(-logf(uv.x)) + logf(-logf(uv.y))
                          + accs[ii][jj];
                if (fabsf(tot) < 2e-3f) {
                    const double* Prd = Pg + ((long)b*SS + i)*HH;
                    const double* Qrd = Qg + ((long)b*SS + j)*HH;
                    double acc = (double)b2[0] - (double)b2[1]
                               - log(-log((double)uv.x))
                               + log(-log((double)uv.y));
                    for (int k = 0; k < 64; ++k) {
                        double v = Prd[k] + Qrd[k];
                        if (v > 0.0)
                            acc += v * ((double)w2[k] - (double)w2[64+k]);
                    }
                    r = (acc >= 0.0) ? 1.0f : 0.0f;
                } else {
                    r = (tot >= 0.f) ? 1.0f : 0.0f;
                }
            }
            out[((long)b*SS + i)*SS + j] = r;
        }
    }
}

extern "C" void kernel_launch(void* const* d_in, const int* in_sizes, int n_in,
                              void* d_out, int out_size, void* d_ws, size_t ws_size,
                              hipStream_t stream) {
    const float* data = (const float*)d_in[0];
    const float* w11  = (const float*)d_in[1];
    const float* b11  = (const float*)d_in[2];
    const float* w12  = (const float*)d_in[3];
    const float* b12  = (const float*)d_in[4];
    const float* w21  = (const float*)d_in[5];
    const float* b21  = (const float*)d_in[6];
    const float* w22  = (const float*)d_in[7];
    const float* b22  = (const float*)d_in[8];
    const float* w31  = (const float*)d_in[9];
    const float* b31  = (const float*)d_in[10];
    const float* wf   = (const float*)d_in[11];
    const float* bf   = (const float*)d_in[12];
    const float* w1   = (const float*)d_in[13];
    const float* b1   = (const float*)d_in[14];
    const float* w2   = (const float*)d_in[15];
    const float* b2   = (const float*)d_in[16];
    const float* gum  = (const float*)d_in[17];
    float* out = (float*)d_out;

    double* T   = (double*)d_ws;            // 11264
    double* Be  = T   + 11264;              // 8192
    double* Qg  = Be  + 8192;               // 262144
    double* Pg  = Qg  + 262144;             // 262144
    double* W1e = Qg;                       // overlay (dead before front)
    double* W2e = W1e + 3072;
    double* wfT = W2e + 5120;
    double* b1e = wfT + 12288;
    double* b2e = b1e + 8192;

    prep1<<<144, 256, 0, stream>>>(w11, w21, w12, w22, b11, b21, b12, b22, wf,
                                   W1e, W2e, wfT, b1e, b2e);
    prep2<<<76, 256, 0, stream>>>(bf, b31, w31, W1e, W2e, wfT, b1e, b2e, T, Be);
    front<<<dim3(8, BB), 512, 0, stream>>>(data, T, Be, w1, b1, Qg, Pg);
    edges<<<dim3(8, BB), 256, 0, stream>>>(Qg, Pg, w2, b2, gum, out);
}

// Round 14
// 55.069 us; speedup vs baseline: 2.5436x; 1.3318x over previous
//
#include <hip/hip_runtime.h>
#include <math.h>

#define BB   32
#define CIN  16
#define HH   64
#define SS   128

// ---------------------------------------------------------------------------
// Composite-weight front-end (R11/R12-verified math):
//   h_pre[n][p] = sum_{c,ti} T[n][c][ti]*xpad[c][p+off(ti)] + B_eff[n][p]
//   taps off(ti), ti=0..10: {-10,-5,-3,-2,-1,0,1,2,3,5,10}
// ---------------------------------------------------------------------------

// prep1 (R12-identical)
__global__ __launch_bounds__(256) void prep1(
    const float* __restrict__ w11, const float* __restrict__ w21,
    const float* __restrict__ w12, const float* __restrict__ w22,
    const float* __restrict__ b11, const float* __restrict__ b21,
    const float* __restrict__ b12, const float* __restrict__ b22,
    const float* __restrict__ wf,
    double* __restrict__ W1e, double* __restrict__ W2e,
    double* __restrict__ wfT, double* __restrict__ b1e,
    double* __restrict__ b2e)
{
    int o = blockIdx.x * 256 + threadIdx.x;
    if (o < 3072) {
        int m = o / 48, r = o % 48, c = r / 3, t = r % 3;
        double a0 = 0, a1 = 0;
        #pragma unroll
        for (int mm = 0; mm < 64; mm += 2) {
            a0 += (double)w12[(m*64+mm)*3+t]   * (double)w11[mm*16+c];
            a1 += (double)w12[(m*64+mm+1)*3+t] * (double)w11[(mm+1)*16+c];
        }
        W1e[o] = a0 + a1;
    } else if (o < 8192) {
        int j = o - 3072;
        int m = j / 80, r = j % 80, c = r / 5, u = r % 5;
        double a0 = 0, a1 = 0;
        #pragma unroll
        for (int mm = 0; mm < 64; mm += 2) {
            a0 += (double)w22[(m*64+mm)*5+u]   * (double)w21[mm*16+c];
            a1 += (double)w22[(m*64+mm+1)*5+u] * (double)w21[(mm+1)*16+c];
        }
        W2e[j] = a0 + a1;
    } else if (o < 20480) {
        int j = o - 8192;
        wfT[j] = (double)wf[(j & 63) * 192 + (j >> 6)];
    } else if (o < 28672) {
        int j = o - 20480; int m = j >> 7, p = j & 127;
        double a = (double)b12[m];
        #pragma unroll
        for (int t = 0; t < 3; ++t) {
            int pos = p + (t - 1) * 3;
            if (pos >= 0 && pos < SS) {
                double s0 = 0, s1 = 0;
                #pragma unroll
                for (int mm = 0; mm < 64; mm += 2) {
                    s0 += (double)w12[(m*64+mm)*3+t]   * (double)b11[mm];
                    s1 += (double)w12[(m*64+mm+1)*3+t] * (double)b11[mm+1];
                }
                a += s0 + s1;
            }
        }
        b1e[j] = a;
    } else if (o < 36864) {
        int j = o - 28672; int m = j >> 7, p = j & 127;
        double a = (double)b22[m];
        #pragma unroll
        for (int u = 0; u < 5; ++u) {
            int pos = p + (u - 2) * 5;
            if (pos >= 0 && pos < SS) {
                double s0 = 0, s1 = 0;
                #pragma unroll
                for (int mm = 0; mm < 64; mm += 2) {
                    s0 += (double)w22[(m*64+mm)*5+u]   * (double)b21[mm];
                    s1 += (double)w22[(m*64+mm+1)*5+u] * (double)b21[mm+1];
                }
                a += s0 + s1;
            }
        }
        b2e[j] = a;
    }
}

// prep2 (R12-identical)
__global__ __launch_bounds__(256) void prep2(
    const float* __restrict__ bf,  const float* __restrict__ b31,
    const float* __restrict__ w31,
    const double* __restrict__ W1e, const double* __restrict__ W2e,
    const double* __restrict__ wfT, const double* __restrict__ b1e,
    const double* __restrict__ b2e,
    double* __restrict__ T, double* __restrict__ Be)
{
    int o = blockIdx.x * 256 + threadIdx.x;
    if (o < 11264) {
        int n = o & 63, k = o >> 6, c = k / 11, ti = k % 11;
        double a0 = 0, a1 = 0;
        if (ti == 2 || ti == 5 || ti == 8) {
            int t = (ti - 2) / 3;
            #pragma unroll
            for (int m = 0; m < 64; m += 2) {
                a0 += wfT[m*64+n]     * W1e[m*48 + c*3 + t];
                a1 += wfT[(m+1)*64+n] * W1e[(m+1)*48 + c*3 + t];
            }
        }
        if (ti == 0 || ti == 1 || ti == 5 || ti == 9 || ti == 10) {
            int u = (ti == 0) ? 0 : (ti == 1) ? 1 : (ti == 5) ? 2 : (ti == 9) ? 3 : 4;
            #pragma unroll
            for (int m = 0; m < 64; m += 2) {
                a0 += wfT[(64+m)*64+n]   * W2e[m*80 + c*5 + u];
                a1 += wfT[(64+m+1)*64+n] * W2e[(m+1)*80 + c*5 + u];
            }
        }
        if (ti >= 3 && ti <= 7) {
            int v = ti - 3;
            #pragma unroll
            for (int m = 0; m < 64; m += 2) {
                a0 += wfT[(128+m)*64+n]   * (double)w31[(m*16+c)*5+v];
                a1 += wfT[(128+m+1)*64+n] * (double)w31[((m+1)*16+c)*5+v];
            }
        }
        T[k*64+n] = a0 + a1;
    } else if (o < 19456) {
        int j = o - 11264; int n = j & 63, p = j >> 6;
        double a0 = (double)bf[n], a1 = 0, a2 = 0;
        #pragma unroll
        for (int m = 0; m < 64; ++m) {
            a0 += wfT[m*64+n]       * b1e[m*128+p];
            a1 += wfT[(64+m)*64+n]  * b2e[m*128+p];
            a2 += wfT[(128+m)*64+n] * (double)b31[m];
        }
        Be[p*64+n] = a0 + a1 + a2;
    }
}

// front (R13-identical)
__global__ __launch_bounds__(512, 1) void front(
    const float* __restrict__ x,   const double* __restrict__ T,
    const double* __restrict__ Be, const float* __restrict__ w1,
    const float* __restrict__ b1,
    double* __restrict__ Qg, double* __restrict__ Pg)
{
    const int b  = blockIdx.y;
    const int s0 = blockIdx.x * 16;
    const int t  = threadIdx.x;
    const int lane = t & 63, wave = t >> 6;
    const int kq = wave & 3, ph = wave >> 2;

    __shared__ float  xl[CIN][37];
    __shared__ float  E[176 * 16];
    __shared__ float  w1L[128 * 65];
    __shared__ double red [4][16][64];
    __shared__ double redP[4][16][64];
    __shared__ double h[64 * 18];
    __shared__ int    COL[11];

    double wT[44];
    #pragma unroll
    for (int kk = 0; kk < 44; ++kk) wT[kk] = T[(kq*44+kk)*64 + lane];

    if (t < 11) { const int offs[11] = {-10,-5,-3,-2,-1,0,1,2,3,5,10}; COL[t] = offs[t] + 10; }
    for (int e = t; e < CIN * 36; e += 512) {
        int c = e / 36, col = e - c * 36;
        int g = s0 - 10 + col;
        xl[c][col] = (g >= 0 && g < SS) ? x[(b * CIN + c) * SS + g] : 0.f;
    }
    for (int e = t; e < 8192; e += 512) {
        int n = e >> 7, k = e & 127;
        w1L[k * 65 + n] = w1[e];
    }
    __syncthreads();                                       // S1
    for (int e = t; e < 2816; e += 512) {
        int k = e >> 4, p = e & 15;
        int c = k / 11, ti = k - c * 11;
        E[e] = xl[c][p + COL[ti]];
    }
    __syncthreads();                                       // S2

    double acc[8];
    #pragma unroll
    for (int q = 0; q < 8; ++q) acc[q] = 0.0;
    #pragma unroll
    for (int kk = 0; kk < 44; ++kk) {
        const float4* dp = (const float4*)(E + (kq*44+kk)*16 + ph*8);
        float4 v0 = dp[0], v1 = dp[1];
        double w = wT[kk];
        acc[0] += (double)v0.x * w; acc[1] += (double)v0.y * w;
        acc[2] += (double)v0.z * w; acc[3] += (double)v0.w * w;
        acc[4] += (double)v1.x * w; acc[5] += (double)v1.y * w;
        acc[6] += (double)v1.z * w; acc[7] += (double)v1.w * w;
    }
    if (kq) { for (int q = 0; q < 8; ++q) red[kq][ph*8+q][lane] = acc[q]; }
    __syncthreads();                                       // S3
    if (!kq) {
        for (int q = 0; q < 8; ++q) {
            int p = ph*8 + q;
            double tot = acc[q] + red[1][p][lane] + red[2][p][lane] + red[3][p][lane]
                       + Be[(s0 + p) * 64 + lane];
            h[lane*18 + p] = tot > 0.0 ? tot : 0.0;
        }
    }
    __syncthreads();                                       // S4

    double aq[8], ap[8];
    #pragma unroll
    for (int q = 0; q < 8; ++q) { aq[q] = 0.0; ap[q] = 0.0; }
    #pragma unroll
    for (int kk = 0; kk < 16; ++kk) {
        int k = kq*16 + kk;
        double q_ = (double)w1L[k * 65 + lane];
        double p_ = (double)w1L[(64 + k) * 65 + lane];
        const double2* hp = (const double2*)(h + k*18 + ph*8);
        double2 d0 = hp[0], d1 = hp[1], d2 = hp[2], d3 = hp[3];
        aq[0] += d0.x*q_; ap[0] += d0.x*p_;  aq[1] += d0.y*q_; ap[1] += d0.y*p_;
        aq[2] += d1.x*q_; ap[2] += d1.x*p_;  aq[3] += d1.y*q_; ap[3] += d1.y*p_;
        aq[4] += d2.x*q_; ap[4] += d2.x*p_;  aq[5] += d2.y*q_; ap[5] += d2.y*p_;
        aq[6] += d3.x*q_; ap[6] += d3.x*p_;  aq[7] += d3.y*q_; ap[7] += d3.y*p_;
    }
    if (kq) {
        for (int q = 0; q < 8; ++q) {
            red [kq][ph*8+q][lane] = aq[q];
            redP[kq][ph*8+q][lane] = ap[q];
        }
    }
    __syncthreads();                                       // S5
    if (!kq) {
        double bv = (double)b1[lane];
        for (int q = 0; q < 8; ++q) {
            int p = ph*8 + q;
            Qg[((long)b*SS + s0 + p)*HH + lane] =
                aq[q] + red[1][p][lane] + red[2][p][lane] + red[3][p][lane];
            Pg[((long)b*SS + s0 + p)*HH + lane] =
                ap[q] + redP[1][p][lane] + redP[2][p][lane] + redP[3][p][lane] + bv;
        }
    }
}

// ---------------------------------------------------------------------------
// edges v5: 16x32 tiles (1024 blocks = 4/CU = 16 waves/CU), 2 edges/thread.
// j = j0 + tj + 16*jj -> Q reads 2-way banks (free, verified conflicts=0).
// f32 screen + f64 fallback for |margin| < 1e-4 (bound: worst-case f32 screen
// error ~2.5e-5 -> 4x margin); fallback fully unrolled, 4 chains.
// ---------------------------------------------------------------------------
__global__ __launch_bounds__(256) void edges(
    const double* __restrict__ Qg, const double* __restrict__ Pg,
    const float* __restrict__ w2, const float* __restrict__ b2,
    const float* __restrict__ gum, float* __restrict__ out)
{
    const int b  = blockIdx.y;
    const int it = blockIdx.x >> 2;      // 8 i-tiles of 16
    const int jt = blockIdx.x & 3;       // 4 j-tiles of 32
    const int i0 = it * 16, j0 = jt * 32;
    const int t  = threadIdx.x;
    const int ti = t >> 4, tj = t & 15;
    const int i  = i0 + ti;

    if (j0 + 31 < i0) {                  // tile fully below diagonal
        out[((long)b*SS + i)*SS + j0 + tj]      = 0.f;
        out[((long)b*SS + i)*SS + j0 + tj + 16] = 0.f;
        return;
    }

    __shared__ float Pl[16][68];
    __shared__ float Ql[32][68];
    __shared__ float dwl[64];

    if (t < 64) dwl[t] = w2[t] - w2[64 + t];
    for (int e = t; e < 1024; e += 256) {
        int r = e >> 6, c = e & 63;
        Pl[r][c] = (float)Pg[((long)b*SS + i0 + r)*HH + c];
    }
    for (int e = t; e < 2048; e += 256) {
        int r = e >> 6, c = e & 63;
        Ql[r][c] = (float)Qg[((long)b*SS + j0 + r)*HH + c];
    }
    __syncthreads();

    float a0 = 0.f, a1 = 0.f;
    const float4* P0 = (const float4*)&Pl[ti][0];
    const float4* Q0 = (const float4*)&Ql[tj][0];
    const float4* Q1 = (const float4*)&Ql[tj + 16][0];
    const float4* DW = (const float4*)dwl;
#define RDOT(acc, pv, qv, dw) { float v; \
    v = pv.x + qv.x; v = v > 0.f ? v : 0.f; acc += v * dw.x; \
    v = pv.y + qv.y; v = v > 0.f ? v : 0.f; acc += v * dw.y; \
    v = pv.z + qv.z; v = v > 0.f ? v : 0.f; acc += v * dw.z; \
    v = pv.w + qv.w; v = v > 0.f ? v : 0.f; acc += v * dw.w; }
    #pragma unroll
    for (int k4 = 0; k4 < 16; ++k4) {
        float4 pv = P0[k4], dw = DW[k4];
        float4 q0 = Q0[k4], q1 = Q1[k4];
        RDOT(a0, pv, q0, dw)
        RDOT(a1, pv, q1, dw)
    }
#undef RDOT
    const float db2 = b2[0] - b2[1];
    float accs[2] = {a0, a1};
    for (int jj = 0; jj < 2; ++jj) {
        int j = j0 + tj + 16*jj;
        float r = 0.f;
        if (j > i) {
            long e = (long)b*SS*SS + (long)i*SS + j;
            float2 uv = *(const float2*)(gum + e*2);
            float tot = db2 - logf(-logf(uv.x)) + logf(-logf(uv.y)) + accs[jj];
            if (fabsf(tot) < 1e-4f) {            // exact f64 recompute (rare)
                const double* Prd = Pg + ((long)b*SS + i)*HH;
                const double* Qrd = Qg + ((long)b*SS + j)*HH;
                double s0=0, s1=0, s2=0, s3=0;
                #pragma unroll
                for (int k = 0; k < 64; k += 4) {
                    double v0 = Prd[k]   + Qrd[k];
                    double v1 = Prd[k+1] + Qrd[k+1];
                    double v2 = Prd[k+2] + Qrd[k+2];
                    double v3 = Prd[k+3] + Qrd[k+3];
                    if (v0 > 0.0) s0 += v0 * ((double)w2[k]   - (double)w2[64+k]);
                    if (v1 > 0.0) s1 += v1 * ((double)w2[k+1] - (double)w2[64+k+1]);
                    if (v2 > 0.0) s2 += v2 * ((double)w2[k+2] - (double)w2[64+k+2]);
                    if (v3 > 0.0) s3 += v3 * ((double)w2[k+3] - (double)w2[64+k+3]);
                }
                double accd = (double)b2[0] - (double)b2[1]
                            - log(-log((double)uv.x)) + log(-log((double)uv.y))
                            + ((s0 + s1) + (s2 + s3));
                r = (accd >= 0.0) ? 1.0f : 0.0f;
            } else {
                r = (tot >= 0.f) ? 1.0f : 0.0f;
            }
        }
        out[((long)b*SS + i)*SS + j] = r;
    }
}

extern "C" void kernel_launch(void* const* d_in, const int* in_sizes, int n_in,
                              void* d_out, int out_size, void* d_ws, size_t ws_size,
                              hipStream_t stream) {
    const float* data = (const float*)d_in[0];
    const float* w11  = (const float*)d_in[1];
    const float* b11  = (const float*)d_in[2];
    const float* w12  = (const float*)d_in[3];
    const float* b12  = (const float*)d_in[4];
    const float* w21  = (const float*)d_in[5];
    const float* b21  = (const float*)d_in[6];
    const float* w22  = (const float*)d_in[7];
    const float* b22  = (const float*)d_in[8];
    const float* w31  = (const float*)d_in[9];
    const float* b31  = (const float*)d_in[10];
    const float* wf   = (const float*)d_in[11];
    const float* bf   = (const float*)d_in[12];
    const float* w1   = (const float*)d_in[13];
    const float* b1   = (const float*)d_in[14];
    const float* w2   = (const float*)d_in[15];
    const float* b2   = (const float*)d_in[16];
    const float* gum  = (const float*)d_in[17];
    float* out = (float*)d_out;

    double* T   = (double*)d_ws;            // 11264
    double* Be  = T   + 11264;              // 8192
    double* Qg  = Be  + 8192;               // 262144
    double* Pg  = Qg  + 262144;             // 262144
    double* W1e = Qg;                       // overlay (dead before front)
    double* W2e = W1e + 3072;
    double* wfT = W2e + 5120;
    double* b1e = wfT + 12288;
    double* b2e = b1e + 8192;

    prep1<<<144, 256, 0, stream>>>(w11, w21, w12, w22, b11, b21, b12, b22, wf,
                                   W1e, W2e, wfT, b1e, b2e);
    prep2<<<76, 256, 0, stream>>>(bf, b31, w31, W1e, W2e, wfT, b1e, b2e, T, Be);
    front<<<dim3(8, BB), 512, 0, stream>>>(data, T, Be, w1, b1, Qg, Pg);
    edges<<<dim3(32, BB), 256, 0, stream>>>(Qg, Pg, w2, b2, gum, out);
}

// Round 15
// 50.398 us; speedup vs baseline: 2.7794x; 1.0927x over previous
//
#include <hip/hip_runtime.h>
#include <math.h>

#define BB   32
#define CIN  16
#define HH   64
#define SS   128

// ---------------------------------------------------------------------------
// Composite-weight front-end (R11..R14-verified math):
//   h_pre[n][p] = sum_{c,ti} T[n][c][ti]*xpad[c][p+off(ti)] + B_eff[n][p]
//   taps off(ti), ti=0..10: {-10,-5,-3,-2,-1,0,1,2,3,5,10}
//   path1 (w12 o w11): ti {2,5,8}; path2 (w22 o w21): ti {0,1,5,9,10};
//   path3 (w31): ti {3..7}
// ---------------------------------------------------------------------------

// Fused prep: one launch. T-blocks (0..43) recompute their 4-column W-slices
// in LDS; Be-blocks (44..75) use the exact piecewise-indicator decomposition:
//   b1e[m][p] = b12[m] + SW1[m][1] + (p>=3)SW1[m][0] + (p<=124)SW1[m][2]
//   b2e[m][p] = b22[m] + SW2[m][2] + (p>=10)SW2[m][0] + (p>=5)SW2[m][1]
//                       + (p<=122)SW2[m][3] + (p<=117)SW2[m][4]
__global__ __launch_bounds__(256) void prep(
    const float* __restrict__ w11, const float* __restrict__ w21,
    const float* __restrict__ w12, const float* __restrict__ w22,
    const float* __restrict__ w31, const float* __restrict__ wf,
    const float* __restrict__ bf,
    const float* __restrict__ b11, const float* __restrict__ b21,
    const float* __restrict__ b12, const float* __restrict__ b22,
    const float* __restrict__ b31,
    double* __restrict__ T, double* __restrict__ Be)
{
    __shared__ float  wfl[192 * 65];     // wfl[m*65+n] = wf[n*192+m]
    __shared__ double W1s[4][64];
    __shared__ double W2s[4][64];
    __shared__ double SW1s[64][3];
    __shared__ double SW2s[64][5];

    const int tid = threadIdx.x;
    const int bx  = blockIdx.x;

    for (int e = tid; e < 12288; e += 256) {       // stage wf transposed
        int n = e / 192, m = e - n * 192;
        wfl[m * 65 + n] = wf[e];
    }

    if (bx < 44) {
        // ---- T outputs o = bx*256+tid; k = bx*4+slot; n = lane -------------
        const int slot = tid >> 6, n = tid & 63;
        const int k = bx * 4 + slot, c = k / 11, ti = k % 11;
        const bool p1 = (ti == 2 || ti == 5 || ti == 8);
        const bool p2 = (ti == 0 || ti == 1 || ti == 5 || ti == 9 || ti == 10);
        const bool p3 = (ti >= 3 && ti <= 7);
        if (p1) {                                   // W1 slice (this slot)
            int t = (ti - 2) / 3;
            double s0 = 0, s1 = 0;
            #pragma unroll
            for (int mm = 0; mm < 64; mm += 2) {
                s0 += (double)w12[(n*64+mm)*3+t]   * (double)w11[mm*16+c];
                s1 += (double)w12[(n*64+mm+1)*3+t] * (double)w11[(mm+1)*16+c];
            }
            W1s[slot][n] = s0 + s1;                 // n doubles as m index
        }
        if (p2) {                                   // W2 slice
            int u = (ti == 0) ? 0 : (ti == 1) ? 1 : (ti == 5) ? 2 : (ti == 9) ? 3 : 4;
            double s0 = 0, s1 = 0;
            #pragma unroll
            for (int mm = 0; mm < 64; mm += 2) {
                s0 += (double)w22[(n*64+mm)*5+u]   * (double)w21[mm*16+c];
                s1 += (double)w22[(n*64+mm+1)*5+u] * (double)w21[(mm+1)*16+c];
            }
            W2s[slot][n] = s0 + s1;
        }
        __syncthreads();
        double a0 = 0, a1 = 0;
        if (p1) {
            #pragma unroll
            for (int m = 0; m < 64; m += 2) {
                a0 += (double)wfl[m*65+n]     * W1s[slot][m];
                a1 += (double)wfl[(m+1)*65+n] * W1s[slot][m+1];
            }
        }
        if (p2) {
            #pragma unroll
            for (int m = 0; m < 64; m += 2) {
                a0 += (double)wfl[(64+m)*65+n]   * W2s[slot][m];
                a1 += (double)wfl[(64+m+1)*65+n] * W2s[slot][m+1];
            }
        }
        if (p3) {
            int v = ti - 3;
            #pragma unroll
            for (int m = 0; m < 64; m += 2) {
                a0 += (double)wfl[(128+m)*65+n]   * (double)w31[(m*16+c)*5+v];
                a1 += (double)wfl[(128+m+1)*65+n] * (double)w31[((m+1)*16+c)*5+v];
            }
        }
        T[k * 64 + n] = a0 + a1;
    } else {
        // ---- Be outputs j = (bx-44)*256+tid; p = j>>6 wave-uniform ---------
        for (int q = tid; q < 512; q += 256) {      // SW tables
            if (q < 192) {
                int m = q / 3, t = q - 3 * m;
                double s0 = 0, s1 = 0;
                #pragma unroll
                for (int mm = 0; mm < 64; mm += 2) {
                    s0 += (double)w12[(m*64+mm)*3+t]   * (double)b11[mm];
                    s1 += (double)w12[(m*64+mm+1)*3+t] * (double)b11[mm+1];
                }
                SW1s[m][t] = s0 + s1;
            } else {
                int q2 = q - 192; int m = q2 / 5, u = q2 - 5 * m;
                double s0 = 0, s1 = 0;
                #pragma unroll
                for (int mm = 0; mm < 64; mm += 2) {
                    s0 += (double)w22[(m*64+mm)*5+u]   * (double)b21[mm];
                    s1 += (double)w22[(m*64+mm+1)*5+u] * (double)b21[mm+1];
                }
                SW2s[m][u] = s0 + s1;
            }
        }
        __syncthreads();
        int j = (bx - 44) * 256 + tid;
        int n = tid & 63, p = j >> 6;
        double base = (double)bf[n];
        double d10 = 0, d12 = 0, d20 = 0, d21 = 0, d23 = 0, d24 = 0;
        #pragma unroll
        for (int m = 0; m < 64; ++m) {
            double wa = (double)wfl[m*65+n];
            double wb = (double)wfl[(64+m)*65+n];
            double wc = (double)wfl[(128+m)*65+n];
            base += wa * ((double)b12[m] + SW1s[m][1])
                  + wb * ((double)b22[m] + SW2s[m][2])
                  + wc * (double)b31[m];
            d10 += wa * SW1s[m][0];  d12 += wa * SW1s[m][2];
            d20 += wb * SW2s[m][0];  d21 += wb * SW2s[m][1];
            d23 += wb * SW2s[m][3];  d24 += wb * SW2s[m][4];
        }
        double a = base;
        if (p >= 3)   a += d10;
        if (p <= 124) a += d12;
        if (p >= 10)  a += d20;
        if (p >= 5)   a += d21;
        if (p <= 122) a += d23;
        if (p <= 117) a += d24;
        Be[p * 64 + n] = a;
    }
}

// front (R13/R14-identical)
__global__ __launch_bounds__(512, 1) void front(
    const float* __restrict__ x,   const double* __restrict__ T,
    const double* __restrict__ Be, const float* __restrict__ w1,
    const float* __restrict__ b1,
    double* __restrict__ Qg, double* __restrict__ Pg)
{
    const int b  = blockIdx.y;
    const int s0 = blockIdx.x * 16;
    const int t  = threadIdx.x;
    const int lane = t & 63, wave = t >> 6;
    const int kq = wave & 3, ph = wave >> 2;

    __shared__ float  xl[CIN][37];
    __shared__ float  E[176 * 16];
    __shared__ float  w1L[128 * 65];
    __shared__ double red [4][16][64];
    __shared__ double redP[4][16][64];
    __shared__ double h[64 * 18];
    __shared__ int    COL[11];

    double wT[44];
    #pragma unroll
    for (int kk = 0; kk < 44; ++kk) wT[kk] = T[(kq*44+kk)*64 + lane];

    if (t < 11) { const int offs[11] = {-10,-5,-3,-2,-1,0,1,2,3,5,10}; COL[t] = offs[t] + 10; }
    for (int e = t; e < CIN * 36; e += 512) {
        int c = e / 36, col = e - c * 36;
        int g = s0 - 10 + col;
        xl[c][col] = (g >= 0 && g < SS) ? x[(b * CIN + c) * SS + g] : 0.f;
    }
    for (int e = t; e < 8192; e += 512) {
        int n = e >> 7, k = e & 127;
        w1L[k * 65 + n] = w1[e];
    }
    __syncthreads();                                       // S1
    for (int e = t; e < 2816; e += 512) {
        int k = e >> 4, p = e & 15;
        int c = k / 11, ti = k - c * 11;
        E[e] = xl[c][p + COL[ti]];
    }
    __syncthreads();                                       // S2

    double acc[8];
    #pragma unroll
    for (int q = 0; q < 8; ++q) acc[q] = 0.0;
    #pragma unroll
    for (int kk = 0; kk < 44; ++kk) {
        const float4* dp = (const float4*)(E + (kq*44+kk)*16 + ph*8);
        float4 v0 = dp[0], v1 = dp[1];
        double w = wT[kk];
        acc[0] += (double)v0.x * w; acc[1] += (double)v0.y * w;
        acc[2] += (double)v0.z * w; acc[3] += (double)v0.w * w;
        acc[4] += (double)v1.x * w; acc[5] += (double)v1.y * w;
        acc[6] += (double)v1.z * w; acc[7] += (double)v1.w * w;
    }
    if (kq) { for (int q = 0; q < 8; ++q) red[kq][ph*8+q][lane] = acc[q]; }
    __syncthreads();                                       // S3
    if (!kq) {
        for (int q = 0; q < 8; ++q) {
            int p = ph*8 + q;
            double tot = acc[q] + red[1][p][lane] + red[2][p][lane] + red[3][p][lane]
                       + Be[(s0 + p) * 64 + lane];
            h[lane*18 + p] = tot > 0.0 ? tot : 0.0;
        }
    }
    __syncthreads();                                       // S4

    double aq[8], ap[8];
    #pragma unroll
    for (int q = 0; q < 8; ++q) { aq[q] = 0.0; ap[q] = 0.0; }
    #pragma unroll
    for (int kk = 0; kk < 16; ++kk) {
        int k = kq*16 + kk;
        double q_ = (double)w1L[k * 65 + lane];
        double p_ = (double)w1L[(64 + k) * 65 + lane];
        const double2* hp = (const double2*)(h + k*18 + ph*8);
        double2 d0 = hp[0], d1 = hp[1], d2 = hp[2], d3 = hp[3];
        aq[0] += d0.x*q_; ap[0] += d0.x*p_;  aq[1] += d0.y*q_; ap[1] += d0.y*p_;
        aq[2] += d1.x*q_; ap[2] += d1.x*p_;  aq[3] += d1.y*q_; ap[3] += d1.y*p_;
        aq[4] += d2.x*q_; ap[4] += d2.x*p_;  aq[5] += d2.y*q_; ap[5] += d2.y*p_;
        aq[6] += d3.x*q_; ap[6] += d3.x*p_;  aq[7] += d3.y*q_; ap[7] += d3.y*p_;
    }
    if (kq) {
        for (int q = 0; q < 8; ++q) {
            red [kq][ph*8+q][lane] = aq[q];
            redP[kq][ph*8+q][lane] = ap[q];
        }
    }
    __syncthreads();                                       // S5
    if (!kq) {
        double bv = (double)b1[lane];
        for (int q = 0; q < 8; ++q) {
            int p = ph*8 + q;
            Qg[((long)b*SS + s0 + p)*HH + lane] =
                aq[q] + red[1][p][lane] + red[2][p][lane] + red[3][p][lane];
            Pg[((long)b*SS + s0 + p)*HH + lane] =
                ap[q] + redP[1][p][lane] + redP[2][p][lane] + redP[3][p][lane] + bv;
        }
    }
}

// edges v6: R14 structure + double2 staging (halved load/store instr count).
__global__ __launch_bounds__(256) void edges(
    const double* __restrict__ Qg, const double* __restrict__ Pg,
    const float* __restrict__ w2, const float* __restrict__ b2,
    const float* __restrict__ gum, float* __restrict__ out)
{
    const int b  = blockIdx.y;
    const int it = blockIdx.x >> 2;
    const int jt = blockIdx.x & 3;
    const int i0 = it * 16, j0 = jt * 32;
    const int t  = threadIdx.x;
    const int ti = t >> 4, tj = t & 15;
    const int i  = i0 + ti;

    if (j0 + 31 < i0) {
        out[((long)b*SS + i)*SS + j0 + tj]      = 0.f;
        out[((long)b*SS + i)*SS + j0 + tj + 16] = 0.f;
        return;
    }

    __shared__ float Pl[16][68];
    __shared__ float Ql[32][68];
    __shared__ float dwl[64];

    if (t < 64) dwl[t] = w2[t] - w2[64 + t];
    for (int e = t; e < 512; e += 256) {
        int r = e >> 5, c2 = (e & 31) * 2;
        double2 v = *(const double2*)(Pg + ((long)b*SS + i0 + r)*HH + c2);
        Pl[r][c2] = (float)v.x; Pl[r][c2+1] = (float)v.y;
    }
    for (int e = t; e < 1024; e += 256) {
        int r = e >> 5, c2 = (e & 31) * 2;
        double2 v = *(const double2*)(Qg + ((long)b*SS + j0 + r)*HH + c2);
        Ql[r][c2] = (float)v.x; Ql[r][c2+1] = (float)v.y;
    }
    __syncthreads();

    float a0 = 0.f, a1 = 0.f;
    const float4* P0 = (const float4*)&Pl[ti][0];
    const float4* Q0 = (const float4*)&Ql[tj][0];
    const float4* Q1 = (const float4*)&Ql[tj + 16][0];
    const float4* DW = (const float4*)dwl;
#define RDOT(acc, pv, qv, dw) { float v; \
    v = pv.x + qv.x; v = v > 0.f ? v : 0.f; acc += v * dw.x; \
    v = pv.y + qv.y; v = v > 0.f ? v : 0.f; acc += v * dw.y; \
    v = pv.z + qv.z; v = v > 0.f ? v : 0.f; acc += v * dw.z; \
    v = pv.w + qv.w; v = v > 0.f ? v : 0.f; acc += v * dw.w; }
    #pragma unroll
    for (int k4 = 0; k4 < 16; ++k4) {
        float4 pv = P0[k4], dw = DW[k4];
        float4 q0 = Q0[k4], q1 = Q1[k4];
        RDOT(a0, pv, q0, dw)
        RDOT(a1, pv, q1, dw)
    }
#undef RDOT
    const float db2 = b2[0] - b2[1];
    float accs[2] = {a0, a1};
    for (int jj = 0; jj < 2; ++jj) {
        int j = j0 + tj + 16*jj;
        float r = 0.f;
        if (j > i) {
            long e = (long)b*SS*SS + (long)i*SS + j;
            float2 uv = *(const float2*)(gum + e*2);
            float tot = db2 - logf(-logf(uv.x)) + logf(-logf(uv.y)) + accs[jj];
            if (fabsf(tot) < 1e-4f) {            // exact f64 recompute (rare)
                const double* Prd = Pg + ((long)b*SS + i)*HH;
                const double* Qrd = Qg + ((long)b*SS + j)*HH;
                double s0=0, s1=0, s2=0, s3=0;
                #pragma unroll
                for (int k = 0; k < 64; k += 4) {
                    double v0 = Prd[k]   + Qrd[k];
                    double v1 = Prd[k+1] + Qrd[k+1];
                    double v2 = Prd[k+2] + Qrd[k+2];
                    double v3 = Prd[k+3] + Qrd[k+3];
                    if (v0 > 0.0) s0 += v0 * ((double)w2[k]   - (double)w2[64+k]);
                    if (v1 > 0.0) s1 += v1 * ((double)w2[k+1] - (double)w2[64+k+1]);
                    if (v2 > 0.0) s2 += v2 * ((double)w2[k+2] - (double)w2[64+k+2]);
                    if (v3 > 0.0) s3 += v3 * ((double)w2[k+3] - (double)w2[64+k+3]);
                }
                double accd = (double)b2[0] - (double)b2[1]
                            - log(-log((double)uv.x)) + log(-log((double)uv.y))
                            + ((s0 + s1) + (s2 + s3));
                r = (accd >= 0.0) ? 1.0f : 0.0f;
            } else {
                r = (tot >= 0.f) ? 1.0f : 0.0f;
            }
        }
        out[((long)b*SS + i)*SS + j] = r;
    }
}

extern "C" void kernel_launch(void* const* d_in, const int* in_sizes, int n_in,
                              void* d_out, int out_size, void* d_ws, size_t ws_size,
                              hipStream_t stream) {
    const float* data = (const float*)d_in[0];
    const float* w11  = (const float*)d_in[1];
    const float* b11  = (const float*)d_in[2];
    const float* w12  = (const float*)d_in[3];
    const float* b12  = (const float*)d_in[4];
    const float* w21  = (const float*)d_in[5];
    const float* b21  = (const float*)d_in[6];
    const float* w22  = (const float*)d_in[7];
    const float* b22  = (const float*)d_in[8];
    const float* w31  = (const float*)d_in[9];
    const float* b31  = (const float*)d_in[10];
    const float* wf   = (const float*)d_in[11];
    const float* bf   = (const float*)d_in[12];
    const float* w1   = (const float*)d_in[13];
    const float* b1   = (const float*)d_in[14];
    const float* w2   = (const float*)d_in[15];
    const float* b2   = (const float*)d_in[16];
    const float* gum  = (const float*)d_in[17];
    float* out = (float*)d_out;

    double* T  = (double*)d_ws;             // 11264
    double* Be = T  + 11264;                // 8192
    double* Qg = Be + 8192;                 // 262144
    double* Pg = Qg + 262144;               // 262144  (total ~4.35 MB)

    prep<<<76, 256, 0, stream>>>(w11, w21, w12, w22, w31, wf, bf,
                                 b11, b21, b12, b22, b31, T, Be);
    front<<<dim3(8, BB), 512, 0, stream>>>(data, T, Be, w1, b1, Qg, Pg);
    edges<<<dim3(32, BB), 256, 0, stream>>>(Qg, Pg, w2, b2, gum, out);
}